// Round 3
// baseline (32.057 us; speedup 1.0000x reference)
//
#include <hip/hip_runtime.h>
#include <hip/hip_bf16.h>
#include <math.h>

#define NCELL 32
#define P 128
#define C 4
#define KSEL 64
#define THRESH 0.7f
#define NEGV -1e9f

// d_ws float layout:
//  [0 .. 436]          R (see slot map below), [437..511] unused
//  [512 .. 512+128*96) QWT: row i (0..127), stride 96; cols:
//        0..63  q_w(c,m,i)*w_w(n,i)   col = c*16 + m*4 + n
//        64..79 q_b(m,i)*w_w(n,i)     col = 64 + m*4 + n
//        80..83 w_w(n,i)              col = 80 + n
// R slot map:
//   0..255  KV[c][d][mn]   K(c,m).V(d,n)
// 256..319  KBB[c][mn]     K(c,m).VB(n) + KB(m).V(c,n)
// 320..335  KB0[mn]        KB(m).VB(n)
// 336..399  Gfull[c][mn]   Q(c,m).WW(n)      (unmasked)
// 400..415  G0full[mn]     QB(m).WW(n)       (unmasked)
// 416..431  VS[d][n]       rowsum V(d,n)
// 432..435  VBs[n]         rowsum VB(n)
// 436       w_b[0]
#define R_OFF 0
#define QWT_OFF 512
#define QWT_STRIDE 96

__global__ __launch_bounds__(512) void precomp_kernel(
    const float* __restrict__ q_w, const float* __restrict__ q_b,
    const float* __restrict__ k_w, const float* __restrict__ k_b,
    const float* __restrict__ v_w, const float* __restrict__ v_b,
    const float* __restrict__ w_w, const float* __restrict__ w_b,
    float* __restrict__ ws)
{
  __shared__ __align__(16) float sQ[2048], sK[2048], sV[2048];
  __shared__ __align__(16) float sWW[512], sQB[512], sKB[512], sVB[512];
  __shared__ __align__(16) float sONE[128];
  const int t = threadIdx.x;

  // ---- stage all weights, coalesced float4 ----
  ((float4*)sQ)[t] = ((const float4*)q_w)[t];
  ((float4*)sK)[t] = ((const float4*)k_w)[t];
  ((float4*)sV)[t] = ((const float4*)v_w)[t];
  if (t < 128)      ((float4*)sWW)[t]       = ((const float4*)w_w)[t];
  else if (t < 256) ((float4*)sQB)[t - 128] = ((const float4*)q_b)[t - 128];
  else if (t < 384) ((float4*)sKB)[t - 256] = ((const float4*)k_b)[t - 256];
  else              ((float4*)sVB)[t - 384] = ((const float4*)v_b)[t - 384];
  if (t < 128) sONE[t] = 1.f;
  __syncthreads();

  // ---- 436 dots, one per thread ----
  if (t < 436) {
    const float *ra, *rb, *rc = nullptr, *rd = nullptr;
    if (t < 256) {                       // KV
      int c = t >> 6, d = (t >> 4) & 3, mn = t & 15;
      ra = sK + c * 512 + (mn >> 2) * 128; rb = sV + d * 512 + (mn & 3) * 128;
    } else if (t < 320) {                // KBB (two fused dots)
      int e = t - 256, c = e >> 4, mn = e & 15;
      ra = sK + c * 512 + (mn >> 2) * 128; rb = sVB + (mn & 3) * 128;
      rc = sKB + (mn >> 2) * 128;          rd = sV + c * 512 + (mn & 3) * 128;
    } else if (t < 336) {                // KB0
      int mn = t - 320;
      ra = sKB + (mn >> 2) * 128; rb = sVB + (mn & 3) * 128;
    } else if (t < 400) {                // Gfull
      int e = t - 336, c = e >> 4, mn = e & 15;
      ra = sQ + c * 512 + (mn >> 2) * 128; rb = sWW + (mn & 3) * 128;
    } else if (t < 416) {                // G0full
      int mn = t - 400;
      ra = sQB + (mn >> 2) * 128; rb = sWW + (mn & 3) * 128;
    } else if (t < 432) {                // VS rowsum
      int e = t - 416;
      ra = sV + (e >> 2) * 512 + (e & 3) * 128; rb = sONE;
    } else {                             // VBs rowsum
      ra = sVB + (t - 432) * 128; rb = sONE;
    }
    const float4* a4 = (const float4*)ra;
    const float4* b4 = (const float4*)rb;
    float s0 = 0.f, s1 = 0.f, s2 = 0.f, s3 = 0.f;
    int rot = t & 31;
    #pragma unroll
    for (int kk = 0; kk < 32; ++kk) {
      int k = (kk + rot) & 31;
      float4 av = a4[k], bv = b4[k];
      s0 += av.x * bv.x; s1 += av.y * bv.y;
      s2 += av.z * bv.z; s3 += av.w * bv.w;
    }
    if (rc) {
      const float4* c4 = (const float4*)rc;
      const float4* d4 = (const float4*)rd;
      #pragma unroll
      for (int kk = 0; kk < 32; ++kk) {
        int k = (kk + rot) & 31;
        float4 av = c4[k], bv = d4[k];
        s0 += av.x * bv.x; s1 += av.y * bv.y;
        s2 += av.z * bv.z; s3 += av.w * bv.w;
      }
    }
    ws[R_OFF + t] = (s0 + s1) + (s2 + s3);
  } else if (t == 436) {
    ws[R_OFF + 436] = w_b[0];
  }

  // ---- QWT product table: row i = t&127, 21 cols per thread ----
  {
    int i = t & 127, qq = t >> 7;
    #pragma unroll
    for (int cc = 0; cc < 21; ++cc) {
      int col = qq * 21 + cc;
      float v;
      if (col < 64) {
        int c = col >> 4, mn = col & 15;
        v = sQ[c * 512 + (mn >> 2) * 128 + i] * sWW[(mn & 3) * 128 + i];
      } else if (col < 80) {
        int mn = col - 64;
        v = sQB[(mn >> 2) * 128 + i] * sWW[(mn & 3) * 128 + i];
      } else {
        v = sWW[(col - 80) * 128 + i];
      }
      ws[QWT_OFF + i * QWT_STRIDE + col] = v;
    }
  }
}

__global__ __launch_bounds__(128) void cell_kernel(
    const float* __restrict__ pts,      // [NCELL][P][C]
    const void*  __restrict__ maskp,    // [NCELL][P] (dtype sniffed)
    const float* __restrict__ pos,      // [P][C]
    const float* __restrict__ ws,
    float* __restrict__ out)            // [NCELL*KSEL*C] ++ [NCELL*KSEL]
{
  __shared__ __align__(16) float sR[448];
  __shared__ float sG[84];              // 0..63 G, 64..79 G0, 80..83 WU
  __shared__ float wbuf[P];
  __shared__ unsigned char selb[P];
  __shared__ int ulist[P];
  __shared__ int slotp[KSEL];
  __shared__ int s_ucnt, s_cnt, s_fv;

  const int cell = blockIdx.x;
  const int t = threadIdx.x;
  const int p = t;

  // ---- mask dtype detection (uniform) ----
  int mkind;
  {
    const unsigned* u = (const unsigned*)maskp;
    bool i32ok = true, f32ok = true;
    for (int k = 0; k < 8; ++k) {
      unsigned v = u[k];
      if (v != 0u && v != 1u) i32ok = false;
      if (v != 0u && v != 0x3f800000u) f32ok = false;
    }
    mkind = (i32ok || f32ok) ? 0 : 1;
  }

  if (t < 112) ((float4*)sR)[t] = ((const float4*)ws)[t];   // stage R
  if (t == 0) { s_ucnt = 0; s_fv = P; }
  bool mv;
  if (mkind == 0) mv = ((const unsigned*)maskp)[cell * P + t] != 0u;
  else            mv = ((const unsigned char*)maskp)[cell * P + t] != 0;
  __syncthreads();

  if (!mv) { int q = atomicAdd(&s_ucnt, 1); ulist[q] = t; }
  else     atomicMin(&s_fv, t);
  __syncthreads();

  // ---- sparse corrections: G = Gfull - sum_U, WU = sum_U ----
  const int ucnt = s_ucnt;
  if (t < 84) {
    float acc = 0.f;
    for (int j = 0; j < ucnt; ++j)
      acc += ws[QWT_OFF + ulist[j] * QWT_STRIDE + t];
    float g;
    if (t < 64)      g = sR[336 + t] - acc;
    else if (t < 80) g = sR[400 + (t - 64)] - acc;
    else             g = acc;                       // WU[n]
    sG[t] = g;
  }
  __syncthreads();

  // ---- per-point score ----
  float4 pv4 = ((const float4*)pts)[cell * P + p];
  float4 po4 = ((const float4*)pos)[p];
  float x[C] = {pv4.x + po4.x, pv4.y + po4.y, pv4.z + po4.z, pv4.w + po4.w};

  float t1 = 0.f;
  #pragma unroll
  for (int mn = 0; mn < 16; ++mn) {
    float A = sG[64 + mn];
    #pragma unroll
    for (int c = 0; c < C; ++c) A += x[c] * sG[(c << 4) + mn];
    float Bv = sR[320 + mn];
    #pragma unroll
    for (int c = 0; c < C; ++c) Bv += x[c] * sR[256 + (c << 4) + mn];
    #pragma unroll
    for (int c = 0; c < C; ++c)
      #pragma unroll
      for (int d = 0; d < C; ++d) Bv += x[c] * x[d] * sR[(c << 6) + (d << 4) + mn];
    t1 += A * Bv;
  }
  const float scale = 0.0883883476483184f; // 1/sqrt(128)
  float t2 = 0.f;
  #pragma unroll
  for (int n = 0; n < 4; ++n) {
    float sv = sR[432 + n];
    #pragma unroll
    for (int d = 0; d < C; ++d) sv += x[d] * sR[416 + (d << 2) + n];
    t2 += sG[80 + n] * sv;
  }
  float S = t1 * scale + NEGV * t2 + sR[436];
  float sig = 1.f / (1.f + expf(-S));
  float wv = mv ? sig : 0.f;
  wbuf[p] = wv;
  selb[p] = (wv > THRESH && mv) ? 1 : 0;
  __syncthreads();

  // ---- count + ranks (proven logic) ----
  {
    int cnt = 0, rank_asc = 0, rank_top = 0;
    float wp = wbuf[p];
    for (int q = 0; q < P; ++q) {
      if (selb[q]) {
        ++cnt;
        if (q < p) ++rank_asc;
        float wq = wbuf[q];
        if (wq > wp || (wq == wp && q < p)) ++rank_top;  // lax.top_k tie-break
      }
    }
    int rank = (cnt > KSEL) ? rank_top : rank_asc;
    if (selb[p] && rank < KSEL) slotp[rank] = p;
    if (t == 0) s_cnt = cnt;
  }
  __syncthreads();

  // ---- write outputs ----
  float* out_pts = out;                       // [NCELL][KSEL][C]
  float* out_w   = out + NCELL * KSEL * C;    // [NCELL][KSEL]
  if (t < KSEL) {
    int k = t;
    int cnt_ = s_cnt;
    float pw = 0.f;
    float4 pvo = {0.f, 0.f, 0.f, 0.f};
    if (cnt_ == 0) {
      if (k == 0 && s_fv < P) {
        pvo = ((const float4*)pts)[cell * P + s_fv];
        pw = wbuf[s_fv];
      }
    } else {
      int nval = cnt_ < KSEL ? cnt_ : KSEL;
      if (k < nval) {
        int p0 = slotp[k];
        pvo = ((const float4*)pts)[cell * P + p0];
        pw = wbuf[p0];
      }
    }
    ((float4*)out_pts)[cell * KSEL + k] = pvo;
    out_w[cell * KSEL + k] = pw;
  }
}

extern "C" void kernel_launch(void* const* d_in, const int* in_sizes, int n_in,
                              void* d_out, int out_size, void* d_ws, size_t ws_size,
                              hipStream_t stream) {
  const float* pts  = (const float*)d_in[0];
  const void*  msk  = (const void*)d_in[1];
  const float* pos  = (const float*)d_in[2];
  const float* q_w  = (const float*)d_in[3];
  const float* q_b  = (const float*)d_in[4];
  const float* k_w  = (const float*)d_in[5];
  const float* k_b  = (const float*)d_in[6];
  const float* v_w  = (const float*)d_in[7];
  const float* v_b  = (const float*)d_in[8];
  const float* w_w  = (const float*)d_in[9];
  const float* w_b  = (const float*)d_in[10];
  float* ws = (float*)d_ws;
  float* out = (float*)d_out;

  precomp_kernel<<<1, 512, 0, stream>>>(q_w, q_b, k_w, k_b, v_w, v_b, w_w, w_b, ws);
  cell_kernel<<<NCELL, 128, 0, stream>>>(pts, msk, pos, ws, out);
}

// Round 4
// 18.864 us; speedup vs baseline: 1.6993x; 1.6993x over previous
//
#include <hip/hip_runtime.h>
#include <hip/hip_bf16.h>
#include <math.h>

#define NCELL 32
#define P 128
#define C 4
#define KSEL 64
#define THRESH 0.7f
#define NEGV -1e9f

__global__ __launch_bounds__(256) void pillar_attn_sample_kernel(
    const float* __restrict__ pts,      // [NCELL][P][C]
    const void*  __restrict__ maskp,    // [NCELL][P]  (dtype sniffed)
    const float* __restrict__ pos,      // [P][C]
    const float* __restrict__ q_w, const float* __restrict__ q_b,
    const float* __restrict__ k_w, const float* __restrict__ k_b,
    const float* __restrict__ v_w, const float* __restrict__ v_b,
    const float* __restrict__ w_w, const float* __restrict__ w_b,
    float* __restrict__ out)            // [NCELL*KSEL*C] ++ [NCELL*KSEL]
{
  // ---- LDS ----
  __shared__ __align__(16) float sQ[2048];   // q_w  [4][512]
  __shared__ __align__(16) float sK[2048];   // k_w
  __shared__ __align__(16) float sV[2048];   // v_w
  __shared__ __align__(16) float sWW[512];   // w_w
  __shared__ __align__(16) float sQB[512];   // q_b
  __shared__ __align__(16) float sKB[512];   // k_b
  __shared__ __align__(16) float sVB[512];   // v_b
  __shared__ __align__(16) float sWM[512];   // masked w_w
  __shared__ __align__(16) float sONE[128];  // ones
  __shared__ __align__(16) float sR[512];    // dot results (508 used)
  __shared__ float wbuf[P];
  __shared__ unsigned long long sBM[2];      // sel ballots (p 0..63 / 64..127)
  __shared__ unsigned long long sMM[2];      // mask ballots
  __shared__ int slotp[KSEL];

  const int cell = blockIdx.x;
  const int t = threadIdx.x;

  // ---- mask dtype detection (uniform) ----
  int mkind;
  {
    const unsigned* u = (const unsigned*)maskp;
    bool i32ok = true, f32ok = true;
    #pragma unroll
    for (int k = 0; k < 8; ++k) {
      unsigned v = u[k];
      if (v != 0u && v != 1u) i32ok = false;
      if (v != 0u && v != 0x3f800000u) f32ok = false;
    }
    mkind = (i32ok || f32ok) ? 0 : 1;
  }

  // ---- early global loads (consumed after the dot phase) ----
  float4 pv4, po4;
  float wb0 = w_b[0];
  bool mv = false;
  if (t < P) {
    pv4 = ((const float4*)pts)[cell * P + t];
    po4 = ((const float4*)pos)[t];
    if (mkind == 0) mv = ((const unsigned*)maskp)[cell * P + t] != 0u;
    else            mv = ((const unsigned char*)maskp)[cell * P + t] != 0;
  }

  // ---- stage weights into LDS (coalesced float4, 256 threads) ----
  {
    const float4* q4 = (const float4*)q_w;
    const float4* k4 = (const float4*)k_w;
    const float4* v4 = (const float4*)v_w;
    float4* sQ4 = (float4*)sQ; float4* sK4 = (float4*)sK; float4* sV4 = (float4*)sV;
    sQ4[t] = q4[t]; sQ4[t + 256] = q4[t + 256];
    sK4[t] = k4[t]; sK4[t + 256] = k4[t + 256];
    sV4[t] = v4[t]; sV4[t + 256] = v4[t + 256];
    if (t < 128) {
      ((float4*)sWW)[t] = ((const float4*)w_w)[t];
      ((float4*)sKB)[t] = ((const float4*)k_b)[t];
      sONE[t] = 1.f;
    } else {
      int u = t - 128;
      ((float4*)sQB)[u] = ((const float4*)q_b)[u];
      ((float4*)sVB)[u] = ((const float4*)v_b)[u];
    }
  }
  if (t < P && (t & 63) == 0) { /* placeholder to keep wave convergence */ }
  if (t < P) {
    unsigned long long mm = __ballot(mv);
    if ((t & 63) == 0) sMM[t >> 6] = mm;
  }
  __syncthreads();   // S0: weights + mask ballots visible

  // ---- masked w_w copy (reads mask bits from sMM) ----
  {
    #pragma unroll
    for (int r = 0; r < 2; ++r) {
      int idx = t + r * 256;             // 0..511
      int i = idx & 127;
      int bit = (int)((sMM[i >> 6] >> (i & 63)) & 1ull);
      sWM[idx] = bit ? sWW[idx] : 0.f;
    }
  }
  __syncthreads();   // S1: sWM ready

  // ---- 508 length-128 dots, 2 tasks/thread (verified map) ----
  // 0..255   KV  [c][d][mn] : K(c,m).V(d,n)
  // 256..319 KB1 [c][mn]    : K(c,m).VB(n)
  // 320..383 KB2 [d][mn]    : KB(m).V(d,n)
  // 384..399 KB0 [mn]       : KB(m).VB(n)
  // 400..463 G   [c][mn]    : Q(c,m).WM(n)
  // 464..479 G0  [mn]       : QB(m).WM(n)
  // 480..495 VS  [d][n]     : V(d,n).1
  // 496..499 VBs [n]        : VB(n).1
  // 500..503 WWs [n]        : WW(n).1
  // 504..507 WMs [n]        : WM(n).1
  for (int task = t; task < 508; task += 256) {
    const float* ra; const float* rb;
    if (task < 256) {
      int c = task >> 6, d = (task >> 4) & 3, mn = task & 15;
      ra = sK + c * 512 + (mn >> 2) * 128; rb = sV + d * 512 + (mn & 3) * 128;
    } else if (task < 320) {
      int e = task - 256; int c = e >> 4, mn = e & 15;
      ra = sK + c * 512 + (mn >> 2) * 128; rb = sVB + (mn & 3) * 128;
    } else if (task < 384) {
      int e = task - 320; int d = e >> 4, mn = e & 15;
      ra = sKB + (mn >> 2) * 128; rb = sV + d * 512 + (mn & 3) * 128;
    } else if (task < 400) {
      int mn = task - 384; ra = sKB + (mn >> 2) * 128; rb = sVB + (mn & 3) * 128;
    } else if (task < 464) {
      int e = task - 400; int c = e >> 4, mn = e & 15;
      ra = sQ + c * 512 + (mn >> 2) * 128; rb = sWM + (mn & 3) * 128;
    } else if (task < 480) {
      int mn = task - 464; ra = sQB + (mn >> 2) * 128; rb = sWM + (mn & 3) * 128;
    } else if (task < 496) {
      int e = task - 480; ra = sV + (e >> 2) * 512 + (e & 3) * 128; rb = sONE;
    } else if (task < 500) {
      ra = sVB + (task - 496) * 128; rb = sONE;
    } else if (task < 504) {
      ra = sWW + (task - 500) * 128; rb = sONE;
    } else {
      ra = sWM + (task - 504) * 128; rb = sONE;
    }
    const float4* a4 = (const float4*)ra;
    const float4* b4 = (const float4*)rb;
    float s0 = 0.f, s1 = 0.f, s2 = 0.f, s3 = 0.f;
    int rot = t & 31;
    #pragma unroll
    for (int kk = 0; kk < 32; ++kk) {
      int k = (kk + rot) & 31;
      float4 av = a4[k], bv = b4[k];
      s0 += av.x * bv.x; s1 += av.y * bv.y;
      s2 += av.z * bv.z; s3 += av.w * bv.w;
    }
    sR[task] = (s0 + s1) + (s2 + s3);
  }
  __syncthreads();   // S2: dots ready

  // ---- per-point score (float4 broadcast LDS reads) ----
  bool selp = false;
  if (t < P) {
    const int p = t;
    float x[C] = {pv4.x + po4.x, pv4.y + po4.y, pv4.z + po4.z, pv4.w + po4.w};
    float xx[C][C];
    #pragma unroll
    for (int c = 0; c < C; ++c)
      #pragma unroll
      for (int d = 0; d < C; ++d) xx[c][d] = x[c] * x[d];

    const float4* R4 = (const float4*)sR;
    float t1 = 0.f;
    #pragma unroll
    for (int g = 0; g < 4; ++g) {
      float4 A = R4[116 + g];                       // G0
      #pragma unroll
      for (int c = 0; c < C; ++c) {
        float4 gv = R4[100 + c * 4 + g];            // G
        A.x += x[c] * gv.x; A.y += x[c] * gv.y; A.z += x[c] * gv.z; A.w += x[c] * gv.w;
      }
      float4 Bv = R4[96 + g];                       // KB0
      #pragma unroll
      for (int c = 0; c < C; ++c) {
        float4 b1 = R4[64 + c * 4 + g];             // KB1
        float4 b2 = R4[80 + c * 4 + g];             // KB2
        Bv.x += x[c] * (b1.x + b2.x); Bv.y += x[c] * (b1.y + b2.y);
        Bv.z += x[c] * (b1.z + b2.z); Bv.w += x[c] * (b1.w + b2.w);
      }
      #pragma unroll
      for (int c = 0; c < C; ++c)
        #pragma unroll
        for (int d = 0; d < C; ++d) {
          float4 kv = R4[(c * 4 + d) * 4 + g];      // KV
          float s = xx[c][d];
          Bv.x += s * kv.x; Bv.y += s * kv.y; Bv.z += s * kv.z; Bv.w += s * kv.w;
        }
      t1 += A.x * Bv.x + A.y * Bv.y + A.z * Bv.z + A.w * Bv.w;
    }
    const float scale = 0.0883883476483184f; // 1/sqrt(128)
    float4 WU4, sv4;
    {
      float4 wws = R4[125], wms = R4[126];
      WU4.x = wws.x - wms.x; WU4.y = wws.y - wms.y;
      WU4.z = wws.z - wms.z; WU4.w = wws.w - wms.w;
      sv4 = R4[124];                                // VBs
      #pragma unroll
      for (int d = 0; d < C; ++d) {
        float4 vs = R4[120 + d];                    // VS
        sv4.x += x[d] * vs.x; sv4.y += x[d] * vs.y;
        sv4.z += x[d] * vs.z; sv4.w += x[d] * vs.w;
      }
    }
    float t2 = WU4.x * sv4.x + WU4.y * sv4.y + WU4.z * sv4.z + WU4.w * sv4.w;
    float S = t1 * scale + NEGV * t2 + wb0;
    float sig = 1.f / (1.f + expf(-S));
    float wv = mv ? sig : 0.f;
    wbuf[p] = wv;
    selp = (wv > THRESH) && mv;
    unsigned long long bm = __ballot(selp);
    if ((t & 63) == 0) sBM[t >> 6] = bm;
  }
  __syncthreads();   // S3: wbuf + sel ballots ready

  // ---- ranks via ballot popcounts ----
  int cnt = 0;
  unsigned long long bm0 = sBM[0], bm1 = sBM[1];
  cnt = __builtin_popcountll(bm0) + __builtin_popcountll(bm1);
  if (t < P) {
    const int p = t;
    int rank;
    if (cnt > KSEL) {
      float wp = wbuf[p];
      int rank_top = 0;
      for (int q = 0; q < P; ++q) {
        int sq = (int)((q < 64 ? (bm0 >> q) : (bm1 >> (q - 64))) & 1ull);
        if (sq) {
          float wq = wbuf[q];
          if (wq > wp || (wq == wp && q < p)) ++rank_top;
        }
      }
      rank = rank_top;
    } else {
      rank = (p < 64)
           ? __builtin_popcountll(bm0 & ((1ull << p) - 1ull))
           : __builtin_popcountll(bm0) +
             __builtin_popcountll(bm1 & ((1ull << (p - 64)) - 1ull));
    }
    if (selp && rank < KSEL) slotp[rank] = p;
  }
  __syncthreads();   // S4: slotp ready

  // ---- write outputs ----
  float* out_pts = out;                       // [NCELL][KSEL][C]
  float* out_w   = out + NCELL * KSEL * C;    // [NCELL][KSEL]
  if (t < KSEL) {
    unsigned long long mm0 = sMM[0], mm1 = sMM[1];
    int fv = mm0 ? __builtin_ctzll(mm0) : (mm1 ? 64 + __builtin_ctzll(mm1) : P);
    int k = t;
    float pw = 0.f;
    float4 pvo = {0.f, 0.f, 0.f, 0.f};
    if (cnt == 0) {
      if (k == 0 && fv < P) {
        pvo = ((const float4*)pts)[cell * P + fv];
        pw = wbuf[fv];
      }
    } else {
      int nval = cnt < KSEL ? cnt : KSEL;
      if (k < nval) {
        int p0 = slotp[k];
        pvo = ((const float4*)pts)[cell * P + p0];
        pw = wbuf[p0];
      }
    }
    ((float4*)out_pts)[cell * KSEL + k] = pvo;
    out_w[cell * KSEL + k] = pw;
  }
}

extern "C" void kernel_launch(void* const* d_in, const int* in_sizes, int n_in,
                              void* d_out, int out_size, void* d_ws, size_t ws_size,
                              hipStream_t stream) {
  const float* pts  = (const float*)d_in[0];
  const void*  msk  = (const void*)d_in[1];
  const float* pos  = (const float*)d_in[2];
  const float* q_w  = (const float*)d_in[3];
  const float* q_b  = (const float*)d_in[4];
  const float* k_w  = (const float*)d_in[5];
  const float* k_b  = (const float*)d_in[6];
  const float* v_w  = (const float*)d_in[7];
  const float* v_b  = (const float*)d_in[8];
  const float* w_w  = (const float*)d_in[9];
  const float* w_b  = (const float*)d_in[10];
  float* out = (float*)d_out;

  pillar_attn_sample_kernel<<<NCELL, 256, 0, stream>>>(
      pts, msk, pos, q_w, q_b, k_w, k_b, v_w, v_b, w_w, w_b, out);
}